// Round 6
// baseline (339.215 us; speedup 1.0000x reference)
//
#include <hip/hip_runtime.h>
#include <hip/hip_bf16.h>

#define N_NODES 10000
#define N_EDGES 320000
#define N_REL   460
#define N_BASES 30
#define DIM     200
#define KZ      6016   // 30*200=6000 padded to multiple of 32
#define KT      6240   // KZ + 224 (self-term columns appended)
#define NPAD    224    // 224 rows allocated for B (col dim padded)
#define NSTEPS  195    // KT/32
#define NTILES  313    // ceil(10000/32)
#define KSPLIT  5
#define CH_STEPS 39    // NSTEPS / KSPLIT exactly
#define PROWS   10016  // 313*32

using short8  = __attribute__((ext_vector_type(8))) short;
using floatx4 = __attribute__((ext_vector_type(4))) float;

__device__ __forceinline__ unsigned short f2bf(float f) {
    union { float f; unsigned u; } v; v.f = f;
    unsigned u = v.u;
    return (unsigned short)((u + 0x7fffu + ((u >> 16) & 1u)) >> 16);
}

__device__ __forceinline__ short8 pack8(const unsigned short* u) {
    union { unsigned short s[8]; short8 v; } p;
#pragma unroll
    for (int i = 0; i < 8; ++i) p.s[i] = u[i];
    return p.v;
}

// ---------------- sort-by-target (counting sort) ----------------

__global__ void hist_kernel(const int* tgt, int* deg) {
    int e = blockIdx.x * blockDim.x + threadIdx.x;
    if (e < N_EDGES) atomicAdd(&deg[tgt[e]], 1);
}

__global__ __launch_bounds__(1024) void scan_kernel(const int* deg, int* starts,
                                                    int* cursor, float* dinv) {
    __shared__ int part[1024];
    int tid = threadIdx.x;
    const int PER = (N_NODES + 1023) / 1024;  // 10
    int base = tid * PER;
    int s = 0;
    for (int i = 0; i < PER; ++i) { int idx = base + i; if (idx < N_NODES) s += deg[idx]; }
    part[tid] = s; __syncthreads();
    for (int off = 1; off < 1024; off <<= 1) {
        int v = (tid >= off) ? part[tid - off] : 0;
        __syncthreads();
        part[tid] += v;
        __syncthreads();
    }
    int run = (tid > 0) ? part[tid - 1] : 0;
    for (int i = 0; i < PER; ++i) {
        int idx = base + i;
        if (idx < N_NODES) {
            int d = deg[idx];
            starts[idx] = run; cursor[idx] = run;
            dinv[idx] = 1.0f / (float)(d > 0 ? d : 1);
            run += d;
        }
    }
    if (tid == 1023) starts[N_NODES] = part[1023];
}

__global__ void scatter_kernel(const int* src, const int* tgt, const int* etype,
                               int* cursor, int2* sedge) {
    int e = blockIdx.x * blockDim.x + threadIdx.x;
    if (e < N_EDGES) {
        int t = tgt[e];
        int pos = atomicAdd(&cursor[t], 1);
        sedge[pos] = make_int2(src[e], etype[e]);
    }
}

// ---------------- operand prep ----------------
// B_ext[c][k] : k<KZ -> weight[b][kk][c] (k=b*200+kk); k in [KZ,KT) -> selfw[j][c]

__global__ void fill_b_kernel(const float* weight, const float* sw, unsigned short* BW) {
    int idx = blockIdx.x * blockDim.x + threadIdx.x;
    if (idx >= NPAD * KT) return;
    int n = idx / KT, k = idx - n * KT;
    float v = 0.f;
    if (k < KZ) {
        if (n < DIM && k < N_BASES * DIM) {
            int b = k / DIM, kk = k - b * DIM;
            v = weight[(b * DIM + kk) * DIM + n];
        }
    } else {
        int j = k - KZ;
        if (n < DIM && j < DIM) v = sw[j * DIM + n];
    }
    BW[idx] = f2bf(v);
}

// Xbf = bf16(x) (agg gather table) and ZX self cols = bf16(max(deg,1)*x)
__global__ void fill_x_kernel(const float* x, const int* deg,
                              unsigned short* Xbf, unsigned short* ZX) {
    int idx = blockIdx.x * blockDim.x + threadIdx.x;
    if (idx >= N_NODES * NPAD) return;
    int n = idx / NPAD, j = idx - n * NPAD;
    float v = (j < DIM) ? x[(size_t)n * DIM + j] : 0.f;
    if (j < DIM) Xbf[(size_t)n * DIM + j] = f2bf(v);
    int d = deg[n]; if (d < 1) d = 1;
    ZX[(size_t)n * KT + KZ + j] = f2bf((float)d * v);
}

// Cpair[t][m] = bf16(coeff[t][m]) | bf16(coeff[t][m+16])<<16  (m=0..15; cols>=30 zero)
__global__ void fill_cpair_kernel(const float* coeff, unsigned int* Cpair) {
    int idx = blockIdx.x * blockDim.x + threadIdx.x;
    if (idx >= N_REL * 16) return;
    int t = idx >> 4, m = idx & 15;
    unsigned lo = f2bf(coeff[t * N_BASES + m]);
    unsigned hi = (m + 16 < N_BASES) ? f2bf(coeff[t * N_BASES + m + 16]) : 0u;
    Cpair[idx] = lo | (hi << 16);
}

// ---------------- per-target-node aggregation via MFMA ----------------
// Z[n] (30x200) = C_n^T (30 x deg) @ X_n (deg x 200), K padded to 32 with A=0.

__global__ __launch_bounds__(256) void agg_kernel(const unsigned short* __restrict__ Xbf,
                                                  const unsigned int* __restrict__ Cpair,
                                                  const int* __restrict__ starts,
                                                  const int2* __restrict__ sedge,
                                                  unsigned short* __restrict__ ZX) {
    int lane = threadIdx.x & 63;
    int wave = threadIdx.x >> 6;
    int n = blockIdx.x * 4 + wave;            // 2500*4 == 10000 exactly
    int ln = lane & 15, q = lane >> 4;

    floatx4 acc0[13], acc1[13];
#pragma unroll
    for (int f = 0; f < 13; ++f) {
        acc0[f] = (floatx4){0.f, 0.f, 0.f, 0.f};
        acc1[f] = acc0[f];
    }

    int e0 = starts[n], e1 = starts[n + 1];
    for (int kb = e0; kb < e1; kb += 32) {
        int eb = kb + 8 * q;
        unsigned short a0v[8], a1v[8];
        int srcs[8];
#pragma unroll
        for (int j = 0; j < 8; ++j) {
            int e = eb + j;
            int ec = (e < e1) ? e : (e1 - 1);
            int2 sd = sedge[ec];
            unsigned cp = (e < e1) ? Cpair[sd.y * 16 + ln] : 0u;
            a0v[j] = (unsigned short)(cp & 0xffffu);
            a1v[j] = (unsigned short)(cp >> 16);
            srcs[j] = sd.x;
        }
        short8 A0 = pack8(a0v), A1 = pack8(a1v);
#pragma unroll
        for (int f = 0; f < 13; ++f) {
            unsigned short bv[8];
#pragma unroll
            for (int j = 0; j < 8; ++j)
                bv[j] = Xbf[(size_t)srcs[j] * DIM + f * 16 + ln];
            short8 B = pack8(bv);
            acc0[f] = __builtin_amdgcn_mfma_f32_16x16x32_bf16(A0, B, acc0[f], 0, 0, 0);
            acc1[f] = __builtin_amdgcn_mfma_f32_16x16x32_bf16(A1, B, acc1[f], 0, 0, 0);
        }
    }

    unsigned short* zr = ZX + (size_t)n * KT;
#pragma unroll
    for (int f = 0; f < 13; ++f) {
        int d = f * 16 + ln;
        if (d < DIM) {
#pragma unroll
            for (int i = 0; i < 4; ++i) {
                int b0 = q * 4 + i;
                zr[b0 * DIM + d] = f2bf(acc0[f][i]);
                int b1 = 16 + q * 4 + i;
                if (b1 < N_BASES) zr[b1 * DIM + d] = f2bf(acc1[f][i]);
            }
        }
    }
}

// ---------------- GEMM: part[chunk] = A_ext @ B_ext^T over K-chunk ----------------
// Grid (313 tiles, 5 chunks). Block: 32 rows x 208 cols, all 4 waves share one
// K-range; wave w owns col-frags f where f%4==w (4/3/3/3). A tile (32x32 bf16,
// 2 KB) staged per kstep via global_load_lds, double-buffered; B direct from L2.

__global__ __launch_bounds__(256) void gemm_kernel(const unsigned short* __restrict__ A,
                                                   const unsigned short* __restrict__ B,
                                                   float* __restrict__ part) {
    __shared__ __align__(16) unsigned short Abuf[2][32 * 32];  // 2 x 2 KB
    int tid = threadIdx.x;
    int lane = tid & 63, wave = tid >> 6;
    int row0 = blockIdx.x * 32;
    int chunk = blockIdx.y;
    int k0 = chunk * (CH_STEPS * 32);

    // staging: waves 0,1 each load 16 rows x 64 B per kstep
    const unsigned short* gsrc = A;
    unsigned short* ldst0 = &Abuf[0][0];
    unsigned short* ldst1 = &Abuf[1][0];
    if (wave < 2) {
        int r = min(row0 + wave * 16 + (lane >> 2), N_NODES - 1);
        gsrc = A + (size_t)r * KT + k0 + (lane & 3) * 8;
        ldst0 = &Abuf[0][wave * 512];
        ldst1 = &Abuf[1][wave * 512];
    }

    int ln = lane & 15, q = lane >> 4;
    int nf = (wave == 0) ? 4 : 3;     // frags f = wave + 4*i
    const unsigned short* pb0 = B + (size_t)(wave * 16 + ln) * KT + k0 + q * 8;

    floatx4 acc0[4], acc1[4];
#pragma unroll
    for (int i = 0; i < 4; ++i) {
        acc0[i] = (floatx4){0.f, 0.f, 0.f, 0.f};
        acc1[i] = acc0[i];
    }

    if (wave < 2)
        __builtin_amdgcn_global_load_lds((const unsigned int*)gsrc,
                                         (unsigned int*)ldst0, 16, 0, 0);
    __syncthreads();

    int buf = 0;
    for (int kk = 0; kk < CH_STEPS; ++kk) {
        if (wave < 2 && kk + 1 < CH_STEPS)
            __builtin_amdgcn_global_load_lds((const unsigned int*)(gsrc + (size_t)(kk + 1) * 32),
                                             (unsigned int*)(buf ? ldst0 : ldst1), 16, 0, 0);
        const unsigned short* ls = &Abuf[buf][0];
        short8 a0 = *(const short8*)(ls + ln * 32 + q * 8);
        short8 a1 = *(const short8*)(ls + (16 + ln) * 32 + q * 8);
        int k = kk * 32;
#pragma unroll
        for (int i = 0; i < 4; ++i) {
            if (i < nf) {
                short8 b = *(const short8*)(pb0 + (size_t)i * 64 * KT + k);
                acc0[i] = __builtin_amdgcn_mfma_f32_16x16x32_bf16(a0, b, acc0[i], 0, 0, 0);
                acc1[i] = __builtin_amdgcn_mfma_f32_16x16x32_bf16(a1, b, acc1[i], 0, 0, 0);
            }
        }
        __syncthreads();
        buf ^= 1;
    }

    // epilogue: waves own disjoint cols; write partial directly (no reduction)
    float* pbase = part + ((size_t)chunk * PROWS + row0) * 208;
#pragma unroll
    for (int i = 0; i < 4; ++i) {
        if (i < nf) {
            int c = (wave + 4 * i) * 16 + ln;
#pragma unroll
            for (int ii = 0; ii < 4; ++ii) {
                pbase[(q * 4 + ii) * 208 + c]      = acc0[i][ii];
                pbase[(16 + q * 4 + ii) * 208 + c] = acc1[i][ii];
            }
        }
    }
}

// ---------------- reduce: out = dinv * sum(partials) + bias ----------------

__global__ __launch_bounds__(256) void reduce_kernel(const float* __restrict__ part,
                                                     const float* __restrict__ dinv,
                                                     const float* __restrict__ bias,
                                                     float* __restrict__ out) {
    int idx = blockIdx.x * blockDim.x + threadIdx.x;
    if (idx >= N_NODES * 50) return;
    int r = idx / 50, cq = idx - r * 50;
    float4 s = {0.f, 0.f, 0.f, 0.f};
#pragma unroll
    for (int c = 0; c < KSPLIT; ++c) {
        float4 v = *(const float4*)(part + ((size_t)c * PROWS + r) * 208 + cq * 4);
        s.x += v.x; s.y += v.y; s.z += v.z; s.w += v.w;
    }
    float dv = dinv[r];
    float4 b = *(const float4*)(bias + cq * 4);
    float4 o;
    o.x = s.x * dv + b.x; o.y = s.y * dv + b.y;
    o.z = s.z * dv + b.z; o.w = s.w * dv + b.w;
    *(float4*)(out + (size_t)r * DIM + cq * 4) = o;
}

// ---------------- launch ----------------

extern "C" void kernel_launch(void* const* d_in, const int* in_sizes, int n_in,
                              void* d_out, int out_size, void* d_ws, size_t ws_size,
                              hipStream_t stream) {
    const float* x      = (const float*)d_in[0];
    const float* weight = (const float*)d_in[1];
    const float* coeff  = (const float*)d_in[2];
    const float* selfw  = (const float*)d_in[3];
    const float* bias   = (const float*)d_in[4];
    const int*   eidx   = (const int*)d_in[5];
    const int*   etype  = (const int*)d_in[6];
    const int* src = eidx;
    const int* tgt = eidx + N_EDGES;
    float* out = (float*)d_out;

    char* ws = (char*)d_ws;
    size_t off = 0;
    auto carve = [&](size_t bytes) {
        char* p = ws + off;
        off += (bytes + 255) & ~(size_t)255;
        return p;
    };
    unsigned short* ZX   = (unsigned short*)carve((size_t)N_NODES * KT * 2);
    unsigned short* BW   = (unsigned short*)carve((size_t)NPAD * KT * 2);
    float* part   = (float*)carve((size_t)KSPLIT * PROWS * 208 * 4);
    unsigned short* Xbf  = (unsigned short*)carve((size_t)(N_NODES * DIM + 64) * 2);
    unsigned int*  Cpair = (unsigned int*)carve((size_t)N_REL * 16 * 4);
    int*   deg    = (int*)carve((size_t)N_NODES * 4);
    int*   starts = (int*)carve((size_t)(N_NODES + 1) * 4);
    int*   cursor = (int*)carve((size_t)N_NODES * 4);
    float* dinv   = (float*)carve((size_t)N_NODES * 4);
    int2*  sedge  = (int2*)carve((size_t)N_EDGES * 8);

    hipMemsetAsync(deg, 0, (size_t)N_NODES * 4, stream);
    hist_kernel<<<(N_EDGES + 255) / 256, 256, 0, stream>>>(tgt, deg);
    scan_kernel<<<1, 1024, 0, stream>>>(deg, starts, cursor, dinv);
    scatter_kernel<<<(N_EDGES + 255) / 256, 256, 0, stream>>>(src, tgt, etype, cursor, sedge);

    fill_b_kernel<<<(NPAD * KT + 255) / 256, 256, 0, stream>>>(weight, selfw, BW);
    fill_x_kernel<<<(N_NODES * NPAD + 255) / 256, 256, 0, stream>>>(x, deg, Xbf, ZX);
    fill_cpair_kernel<<<(N_REL * 16 + 255) / 256, 256, 0, stream>>>(coeff, Cpair);

    agg_kernel<<<N_NODES / 4, 256, 0, stream>>>(Xbf, Cpair, starts, sedge, ZX);

    dim3 ggrid(NTILES, KSPLIT);
    gemm_kernel<<<ggrid, 256, 0, stream>>>(ZX, BW, part);

    reduce_kernel<<<(N_NODES * 50 + 255) / 256, 256, 0, stream>>>(part, dinv, bias, out);
}